// Round 1
// baseline (771.923 us; speedup 1.0000x reference)
//
#include <hip/hip_runtime.h>

#define TT   2048
#define BB   8
#define DD   1024
#define HD   64        // head dim d
#define MP1  9         // NM + 1
#define NTOK (TT*BB)   // 16384
#define CH   64        // chunk length
#define NC   (TT/CH)   // 32 chunks
#define NSEG (BB*MP1)  // 72 segments
#define KVCOLS 576     // Mp1 * d

// ---------------------------------------------------------------
// Kernel 1: gating — scores = X@Wg + bg, softmax, top-2, renormalize
// one wave per token (4 waves / block)
// ---------------------------------------------------------------
__global__ __launch_bounds__(256) void gate_kernel(
    const float* __restrict__ X, const float* __restrict__ Wg,
    const float* __restrict__ bg,
    int2* __restrict__ idxb, float2* __restrict__ alfb) {
  __shared__ float wgT[8 * DD];            // transposed Wg: [j][i], conflict-free reads
  const int tid = threadIdx.x;
  for (int idx = tid; idx < 8 * DD; idx += 256) {
    int i = idx >> 3, j = idx & 7;
    wgT[j * DD + i] = Wg[idx];
  }
  __syncthreads();
  const int lane = tid & 63, wave = tid >> 6;
  const int tok  = blockIdx.x * 4 + wave;
  const float* xr = X + (size_t)tok * DD;
  float p[8] = {0.f,0.f,0.f,0.f,0.f,0.f,0.f,0.f};
  for (int it = 0; it < 16; it++) {
    int i = it * 64 + lane;
    float x = xr[i];
#pragma unroll
    for (int j = 0; j < 8; j++) p[j] += x * wgT[j * DD + i];
  }
#pragma unroll
  for (int j = 0; j < 8; j++) {
    float v = p[j];
#pragma unroll
    for (int off = 32; off > 0; off >>= 1) v += __shfl_xor(v, off);
    p[j] = v + bg[j];
  }
  if (lane == 0) {
    int i1 = 0; float z1 = p[0];
#pragma unroll
    for (int j = 1; j < 8; j++) if (p[j] > z1) { z1 = p[j]; i1 = j; }
    int i2 = -1; float z2 = -3.0e38f;
#pragma unroll
    for (int j = 0; j < 8; j++) if (j != i1 && p[j] > z2) { z2 = p[j]; i2 = j; }
    // renormalized top-2 softmax weights: e^{z1}/(e^{z1}+e^{z2}), e^{z2}/(...)
    float e   = expf(z2 - z1);
    float inv = 1.0f / (1.0f + e);
    idxb[tok] = make_int2(i1 + 1, i2 + 1);   // shift: 0 reserved for shared memory
    alfb[tok] = make_float2(inv, e * inv);
  }
}

// ---------------------------------------------------------------
// Kernel 2: projection GEMM  (16384 x 1024) @ (1024 x [64|576|576])
// fp32, BM=128 BN=64 BK=16, 8x4 per-thread tile, transposed-A LDS
// blockIdx.x = n-tile (19), blockIdx.y = m-tile (128)
// ---------------------------------------------------------------
__global__ __launch_bounds__(256) void proj_gemm(
    const float* __restrict__ X,
    const float* __restrict__ Wq, const float* __restrict__ bq,
    const float* __restrict__ Wk, const float* __restrict__ bk,
    const float* __restrict__ Wv, const float* __restrict__ bv,
    float* __restrict__ Qb, float* __restrict__ Kall, float* __restrict__ Vall) {
  const int nb = blockIdx.x;
  const float* W; const float* bias; float* Out; int ncols, col0;
  if (nb == 0)      { W = Wq; bias = bq; Out = Qb;   ncols = HD;     col0 = 0; }
  else if (nb < 10) { W = Wk; bias = bk; Out = Kall; ncols = KVCOLS; col0 = (nb - 1)  * 64; }
  else              { W = Wv; bias = bv; Out = Vall; ncols = KVCOLS; col0 = (nb - 10) * 64; }

  __shared__ float AsT[16][132];   // [k][row], padded stride keeps 16B-aligned rows
  __shared__ float Bs[16][64];

  const int tid  = threadIdx.x;
  const int tx   = tid & 15, ty = tid >> 4;
  const int row0 = blockIdx.y * 128;
  const int arow = tid >> 1;
  const int acg  = (tid & 1) * 8;
  const int bc   = (tid & 15) * 4;

  float acc[8][4];
#pragma unroll
  for (int i = 0; i < 8; i++)
#pragma unroll
    for (int j = 0; j < 4; j++) acc[i][j] = 0.f;

  for (int k0 = 0; k0 < DD; k0 += 16) {
    float4 a0 = *(const float4*)&X[(size_t)(row0 + arow) * DD + k0 + acg];
    float4 a1 = *(const float4*)&X[(size_t)(row0 + arow) * DD + k0 + acg + 4];
    float4 bw = *(const float4*)&W[(size_t)(k0 + ty) * ncols + col0 + bc];
    __syncthreads();
    AsT[acg + 0][arow] = a0.x; AsT[acg + 1][arow] = a0.y;
    AsT[acg + 2][arow] = a0.z; AsT[acg + 3][arow] = a0.w;
    AsT[acg + 4][arow] = a1.x; AsT[acg + 5][arow] = a1.y;
    AsT[acg + 6][arow] = a1.z; AsT[acg + 7][arow] = a1.w;
    *(float4*)&Bs[ty][bc] = bw;
    __syncthreads();
#pragma unroll
    for (int kk = 0; kk < 16; kk++) {
      float a[8], bb[4];
      *(float4*)&a[0] = *(const float4*)&AsT[kk][ty * 8];
      *(float4*)&a[4] = *(const float4*)&AsT[kk][ty * 8 + 4];
      *(float4*)&bb[0] = *(const float4*)&Bs[kk][tx * 4];
#pragma unroll
      for (int i = 0; i < 8; i++)
#pragma unroll
        for (int j = 0; j < 4; j++) acc[i][j] += a[i] * bb[j];
    }
  }
#pragma unroll
  for (int i = 0; i < 8; i++) {
    int row = row0 + ty * 8 + i;
    float4 o;
    o.x = acc[i][0] + bias[col0 + tx * 4 + 0];
    o.y = acc[i][1] + bias[col0 + tx * 4 + 1];
    o.z = acc[i][2] + bias[col0 + tx * 4 + 2];
    o.w = acc[i][3] + bias[col0 + tx * 4 + 3];
    *(float4*)&Out[(size_t)row * ncols + col0 + tx * 4] = o;
  }
}

// ---------------------------------------------------------------
// Kernel 3: per-(segment, chunk) S = K_c^T V_c  (k rows masked by routing)
// ---------------------------------------------------------------
__global__ __launch_bounds__(256) void chunk_kv(
    const float* __restrict__ Kall, const float* __restrict__ Vall,
    const int2* __restrict__ idxb, float* __restrict__ Sbuf) {
  __shared__ float Kc[CH * HD];   // [tok][r]
  __shared__ float Vc[CH * HD];   // [tok][c]
  const int chunk = blockIdx.x, seg = blockIdx.y;
  const int b = seg / MP1, m = seg % MP1;
  const int t0 = chunk * CH;
  const int tid = threadIdx.x;
#pragma unroll
  for (int u = 0; u < 4; u++) {
    int idx = tid + u * 256;
    int row = idx >> 4, c4 = (idx & 15) * 4;
    int tokrow = (t0 + row) * BB + b;
    float flag = 1.f;
    if (m != 0) { int2 ix = idxb[tokrow]; flag = (ix.x == m || ix.y == m) ? 1.f : 0.f; }
    float4 kv = *(const float4*)&Kall[(size_t)tokrow * KVCOLS + m * 64 + c4];
    float4 vv = *(const float4*)&Vall[(size_t)tokrow * KVCOLS + m * 64 + c4];
    Kc[row * 64 + c4 + 0] = kv.x * flag;
    Kc[row * 64 + c4 + 1] = kv.y * flag;
    Kc[row * 64 + c4 + 2] = kv.z * flag;
    Kc[row * 64 + c4 + 3] = kv.w * flag;
    *(float4*)&Vc[row * 64 + c4] = vv;
  }
  __syncthreads();
  const int r0 = (tid >> 4) * 4, c0 = (tid & 15) * 4;
  float acc[4][4];
#pragma unroll
  for (int v = 0; v < 4; v++)
#pragma unroll
    for (int w = 0; w < 4; w++) acc[v][w] = 0.f;
  for (int tok = 0; tok < CH; tok++) {
    float k0 = Kc[tok * 64 + r0 + 0];
    float k1 = Kc[tok * 64 + r0 + 1];
    float k2 = Kc[tok * 64 + r0 + 2];
    float k3 = Kc[tok * 64 + r0 + 3];
    float4 vv = *(const float4*)&Vc[tok * 64 + c0];
    acc[0][0] += k0 * vv.x; acc[0][1] += k0 * vv.y; acc[0][2] += k0 * vv.z; acc[0][3] += k0 * vv.w;
    acc[1][0] += k1 * vv.x; acc[1][1] += k1 * vv.y; acc[1][2] += k1 * vv.z; acc[1][3] += k1 * vv.w;
    acc[2][0] += k2 * vv.x; acc[2][1] += k2 * vv.y; acc[2][2] += k2 * vv.z; acc[2][3] += k2 * vv.w;
    acc[3][0] += k3 * vv.x; acc[3][1] += k3 * vv.y; acc[3][2] += k3 * vv.z; acc[3][3] += k3 * vv.w;
  }
  float* Sp = Sbuf + ((size_t)seg * NC + chunk) * 4096;
#pragma unroll
  for (int v = 0; v < 4; v++) {
    float4 o = make_float4(acc[v][0], acc[v][1], acc[v][2], acc[v][3]);
    *(float4*)&Sp[(r0 + v) * 64 + c0] = o;
  }
}

// ---------------------------------------------------------------
// Kernel 4: per-segment exclusive scan over chunks (in place)
// Sbuf[seg][c] <- M0 + sum_{c'<c} S[seg][c']
// ---------------------------------------------------------------
__global__ __launch_bounds__(256) void scan_kernel(
    const float* __restrict__ M0, float* __restrict__ Sbuf) {
  const int seg = blockIdx.x;
  const int tid = threadIdx.x;
  float run[16];
#pragma unroll
  for (int u = 0; u < 16; u++) run[u] = M0[tid + u * 256];
  float* base = Sbuf + (size_t)seg * NC * 4096;
  for (int c = 0; c < NC; c++) {
    float* p = base + c * 4096;
#pragma unroll
    for (int u = 0; u < 16; u++) {
      float s = p[tid + u * 256];
      p[tid + u * 256] = run[u];
      run[u] += s;
    }
  }
}

// ---------------------------------------------------------------
// Kernel 5: per-(segment, chunk) output
// O = Q_c @ M_state + tril_incl(Q_c K_c^T) @ V_c ; atomic scatter * alpha
// ---------------------------------------------------------------
__global__ __launch_bounds__(256) void chunk_out(
    const float* __restrict__ Qb, const float* __restrict__ Kall,
    const float* __restrict__ Vall, const float* __restrict__ Sbuf,
    const int2* __restrict__ idxb, const float2* __restrict__ alfb,
    float* __restrict__ out) {
  __shared__ float QP[CH * HD];   // Q tile, later reused to hold P
  __shared__ float Kt[HD * CH];   // [kdim][token]
  __shared__ float Vc[CH * HD];   // [token][c]
  __shared__ float Ms[HD * HD];   // [r][c]
  const int chunk = blockIdx.x, seg = blockIdx.y;
  const int b = seg / MP1, m = seg % MP1;
  const int t0 = chunk * CH;
  const int tid = threadIdx.x;
  {
    const float* Mp = Sbuf + ((size_t)seg * NC + chunk) * 4096;
#pragma unroll
    for (int u = 0; u < 4; u++) {
      int idx = tid + u * 256;
      *(float4*)&Ms[idx * 4] = *(const float4*)&Mp[idx * 4];
      int row = idx >> 4, c4 = (idx & 15) * 4;
      int tokrow = (t0 + row) * BB + b;
      float flag = 1.f;
      if (m != 0) { int2 ix = idxb[tokrow]; flag = (ix.x == m || ix.y == m) ? 1.f : 0.f; }
      float4 q  = *(const float4*)&Qb[(size_t)tokrow * HD + c4];
      float4 kv = *(const float4*)&Kall[(size_t)tokrow * KVCOLS + m * 64 + c4];
      float4 vv = *(const float4*)&Vall[(size_t)tokrow * KVCOLS + m * 64 + c4];
      *(float4*)&QP[row * 64 + c4] = q;
      Kt[(c4 + 0) * 64 + row] = kv.x * flag;
      Kt[(c4 + 1) * 64 + row] = kv.y * flag;
      Kt[(c4 + 2) * 64 + row] = kv.z * flag;
      Kt[(c4 + 3) * 64 + row] = kv.w * flag;
      *(float4*)&Vc[row * 64 + c4] = vv;
    }
  }
  __syncthreads();
  const int ir0 = (tid >> 4) * 4;
  const int c0  = (tid & 15) * 4;
  float oacc[4][4], pv[4][4];
#pragma unroll
  for (int v = 0; v < 4; v++)
#pragma unroll
    for (int w = 0; w < 4; w++) { oacc[v][w] = 0.f; pv[v][w] = 0.f; }
  // fused: oacc = Q@Ms, pv = Q@K^T (per-thread 4x4 tiles)
  for (int kk = 0; kk < 64; kk++) {
    float q0 = QP[(ir0 + 0) * 64 + kk];
    float q1 = QP[(ir0 + 1) * 64 + kk];
    float q2 = QP[(ir0 + 2) * 64 + kk];
    float q3 = QP[(ir0 + 3) * 64 + kk];
    float4 mv = *(const float4*)&Ms[kk * 64 + c0];
    float4 kv = *(const float4*)&Kt[kk * 64 + c0];
    oacc[0][0] += q0 * mv.x; oacc[0][1] += q0 * mv.y; oacc[0][2] += q0 * mv.z; oacc[0][3] += q0 * mv.w;
    oacc[1][0] += q1 * mv.x; oacc[1][1] += q1 * mv.y; oacc[1][2] += q1 * mv.z; oacc[1][3] += q1 * mv.w;
    oacc[2][0] += q2 * mv.x; oacc[2][1] += q2 * mv.y; oacc[2][2] += q2 * mv.z; oacc[2][3] += q2 * mv.w;
    oacc[3][0] += q3 * mv.x; oacc[3][1] += q3 * mv.y; oacc[3][2] += q3 * mv.z; oacc[3][3] += q3 * mv.w;
    pv[0][0] += q0 * kv.x; pv[0][1] += q0 * kv.y; pv[0][2] += q0 * kv.z; pv[0][3] += q0 * kv.w;
    pv[1][0] += q1 * kv.x; pv[1][1] += q1 * kv.y; pv[1][2] += q1 * kv.z; pv[1][3] += q1 * kv.w;
    pv[2][0] += q2 * kv.x; pv[2][1] += q2 * kv.y; pv[2][2] += q2 * kv.z; pv[2][3] += q2 * kv.w;
    pv[3][0] += q3 * kv.x; pv[3][1] += q3 * kv.y; pv[3][2] += q3 * kv.z; pv[3][3] += q3 * kv.w;
  }
  // causal mask (inclusive diagonal: token's own kv update precedes its output)
#pragma unroll
  for (int v = 0; v < 4; v++)
#pragma unroll
    for (int w = 0; w < 4; w++)
      if (c0 + w > ir0 + v) pv[v][w] = 0.f;
  __syncthreads();   // everyone done reading Q before overwrite
#pragma unroll
  for (int v = 0; v < 4; v++) {
    float4 o = make_float4(pv[v][0], pv[v][1], pv[v][2], pv[v][3]);
    *(float4*)&QP[(ir0 + v) * 64 + c0] = o;   // QP now holds P
  }
  __syncthreads();
  // oacc += P @ V
  for (int j = 0; j < 64; j++) {
    float p0 = QP[(ir0 + 0) * 64 + j];
    float p1 = QP[(ir0 + 1) * 64 + j];
    float p2 = QP[(ir0 + 2) * 64 + j];
    float p3 = QP[(ir0 + 3) * 64 + j];
    float4 vv = *(const float4*)&Vc[j * 64 + c0];
    oacc[0][0] += p0 * vv.x; oacc[0][1] += p0 * vv.y; oacc[0][2] += p0 * vv.z; oacc[0][3] += p0 * vv.w;
    oacc[1][0] += p1 * vv.x; oacc[1][1] += p1 * vv.y; oacc[1][2] += p1 * vv.z; oacc[1][3] += p1 * vv.w;
    oacc[2][0] += p2 * vv.x; oacc[2][1] += p2 * vv.y; oacc[2][2] += p2 * vv.z; oacc[2][3] += p2 * vv.w;
    oacc[3][0] += p3 * vv.x; oacc[3][1] += p3 * vv.y; oacc[3][2] += p3 * vv.z; oacc[3][3] += p3 * vv.w;
  }
#pragma unroll
  for (int v = 0; v < 4; v++) {
    int i = ir0 + v;
    int tokrow = (t0 + i) * BB + b;
    float alpha = 1.f;
    bool routed = true;
    if (m != 0) {
      int2 ix = idxb[tokrow];
      if (ix.x == m)      alpha = alfb[tokrow].x;
      else if (ix.y == m) alpha = alfb[tokrow].y;
      else routed = false;
    }
    if (routed) {
#pragma unroll
      for (int w = 0; w < 4; w++)
        atomicAdd(&out[(size_t)tokrow * HD + c0 + w], alpha * oacc[v][w]);
    }
  }
}

// ---------------------------------------------------------------
extern "C" void kernel_launch(void* const* d_in, const int* in_sizes, int n_in,
                              void* d_out, int out_size, void* d_ws, size_t ws_size,
                              hipStream_t stream) {
  const float* X  = (const float*)d_in[0];
  const float* M0 = (const float*)d_in[1];
  const float* Wq = (const float*)d_in[2];
  const float* bq = (const float*)d_in[3];
  const float* Wk = (const float*)d_in[4];
  const float* bk = (const float*)d_in[5];
  const float* Wv = (const float*)d_in[6];
  const float* bv = (const float*)d_in[7];
  const float* Wg = (const float*)d_in[8];
  const float* bg = (const float*)d_in[9];

  char* ws = (char*)d_ws;
  float*  Qb   = (float*)(ws);                       // 16384*64    =  4,194,304 B
  float*  Kall = (float*)(ws + 4194304ULL);          // 16384*576   = 37,748,736 B
  float*  Vall = (float*)(ws + 41943040ULL);         // 16384*576   = 37,748,736 B
  float*  Sbuf = (float*)(ws + 79691776ULL);         // 72*32*4096  = 37,748,736 B
  int2*   idxb = (int2*)(ws + 117440512ULL);         // 16384*8     =    131,072 B
  float2* alfb = (float2*)(ws + 117571584ULL);       // 16384*8     =    131,072 B

  float* out = (float*)d_out;
  hipMemsetAsync(d_out, 0, (size_t)out_size * sizeof(float), stream);

  gate_kernel<<<NTOK / 4, 256, 0, stream>>>(X, Wg, bg, idxb, alfb);
  proj_gemm<<<dim3(19, 128), 256, 0, stream>>>(X, Wq, bq, Wk, bk, Wv, bv, Qb, Kall, Vall);
  chunk_kv<<<dim3(NC, NSEG), 256, 0, stream>>>(Kall, Vall, idxb, Sbuf);
  scan_kernel<<<NSEG, 256, 0, stream>>>(M0, Sbuf);
  chunk_out<<<dim3(NC, NSEG), 256, 0, stream>>>(Qb, Kall, Vall, Sbuf, idxb, alfb, out);
}

// Round 2
// 338.186 us; speedup vs baseline: 2.2825x; 2.2825x over previous
//
#include <hip/hip_runtime.h>

#define TT   2048
#define BB   8
#define DD   1024
#define HD   64        // head dim d
#define MP1  9         // NM + 1
#define NTOK (TT*BB)   // 16384
#define CH   64        // chunk length
#define NC   (TT/CH)   // 32 chunks
#define NSEG (BB*MP1)  // 72 segments
#define NCAT 1280      // 64 Q + 576 K + 576 V + 64 pad

typedef __attribute__((ext_vector_type(8))) short bf16x8;
typedef __attribute__((ext_vector_type(4))) float f32x4;

static __device__ __forceinline__ unsigned short f2bf(float f) {
  union { float f; unsigned u; } c; c.f = f;
  unsigned r = (c.u + 0x7FFF + ((c.u >> 16) & 1)) >> 16;   // RNE
  return (unsigned short)r;
}
static __device__ __forceinline__ float bf2f(unsigned short s) {
  union { unsigned u; float f; } c; c.u = ((unsigned)s) << 16;
  return c.f;
}

// ---------------------------------------------------------------
// Cast X (fp32) -> Xbf (bf16), 4 elems/thread
// ---------------------------------------------------------------
__global__ __launch_bounds__(256) void cast_x(
    const float* __restrict__ X, unsigned short* __restrict__ Xbf) {
  int i = blockIdx.x * 256 + threadIdx.x;
  float4 v = ((const float4*)X)[i];
  ushort4 o;
  o.x = f2bf(v.x); o.y = f2bf(v.y); o.z = f2bf(v.z); o.w = f2bf(v.w);
  ((ushort4*)Xbf)[i] = o;
}

// ---------------------------------------------------------------
// Build Wt[n][k] (bf16, transposed concat of Wq|Wk|Wv|0) and bcat
// ---------------------------------------------------------------
__global__ __launch_bounds__(256) void cast_w(
    const float* __restrict__ Wq, const float* __restrict__ Wk,
    const float* __restrict__ Wv, const float* __restrict__ bq,
    const float* __restrict__ bk, const float* __restrict__ bv,
    unsigned short* __restrict__ Wt, float* __restrict__ bcat) {
  int idx = blockIdx.x * 256 + threadIdx.x;     // over 1280*1024
  int n = idx >> 10, k = idx & 1023;
  float v = 0.f;
  if (n < 64)        v = Wq[k * 64 + n];
  else if (n < 640)  v = Wk[k * 576 + (n - 64)];
  else if (n < 1216) v = Wv[k * 576 + (n - 640)];
  Wt[idx] = f2bf(v);
  if (idx < NCAT) {
    float b = 0.f;
    if (idx < 64)        b = bq[idx];
    else if (idx < 640)  b = bk[idx - 64];
    else if (idx < 1216) b = bv[idx - 640];
    bcat[idx] = b;
  }
}

// ---------------------------------------------------------------
// Gating — fp32 (top-k selection is discrete; keep exact)
// ---------------------------------------------------------------
__global__ __launch_bounds__(256) void gate_kernel(
    const float* __restrict__ X, const float* __restrict__ Wg,
    const float* __restrict__ bg,
    int2* __restrict__ idxb, float2* __restrict__ alfb) {
  __shared__ float wgT[8 * DD];
  const int tid = threadIdx.x;
  for (int idx = tid; idx < 8 * DD; idx += 256) {
    int i = idx >> 3, j = idx & 7;
    wgT[j * DD + i] = Wg[idx];
  }
  __syncthreads();
  const int lane = tid & 63, wave = tid >> 6;
  const int tok  = blockIdx.x * 4 + wave;
  const float* xr = X + (size_t)tok * DD;
  float p[8] = {0.f,0.f,0.f,0.f,0.f,0.f,0.f,0.f};
  for (int it = 0; it < 16; it++) {
    int i = it * 64 + lane;
    float x = xr[i];
#pragma unroll
    for (int j = 0; j < 8; j++) p[j] += x * wgT[j * DD + i];
  }
#pragma unroll
  for (int j = 0; j < 8; j++) {
    float v = p[j];
#pragma unroll
    for (int off = 32; off > 0; off >>= 1) v += __shfl_xor(v, off);
    p[j] = v + bg[j];
  }
  if (lane == 0) {
    int i1 = 0; float z1 = p[0];
#pragma unroll
    for (int j = 1; j < 8; j++) if (p[j] > z1) { z1 = p[j]; i1 = j; }
    int i2 = -1; float z2 = -3.0e38f;
#pragma unroll
    for (int j = 0; j < 8; j++) if (j != i1 && p[j] > z2) { z2 = p[j]; i2 = j; }
    float e   = expf(z2 - z1);
    float inv = 1.0f / (1.0f + e);
    idxb[tok] = make_int2(i1 + 1, i2 + 1);
    alfb[tok] = make_float2(inv, e * inv);
  }
}

// ---------------------------------------------------------------
// Projection GEMM, bf16 MFMA (m97 structure):
// (16384 x 1024) @ (1024 x 1280) -> Ocat bf16 (+bias)
// BM=BN=128, BK=32, 4 waves, 64x64 per wave, 16x16x32 MFMA
// ---------------------------------------------------------------
__global__ __launch_bounds__(256) void proj_mfma(
    const unsigned short* __restrict__ Xbf, const unsigned short* __restrict__ Wt,
    const float* __restrict__ bcat, unsigned short* __restrict__ Ocat) {
  __shared__ unsigned short As[128 * 32];   // [row][k], 64B row stride
  __shared__ unsigned short Bs[128 * 32];   // [col][k] (W transposed)
  const int tid  = threadIdx.x;
  const int lane = tid & 63, w = tid >> 6;
  const int row0 = blockIdx.y * 128;
  const int col0 = blockIdx.x * 128;
  const int wr = (w >> 1) * 64, wc = (w & 1) * 64;
  const int lrow = lane >> 2;            // 0..15
  const int lk   = (lane & 3) * 8;       // bf16 elems

  f32x4 acc[4][4];
#pragma unroll
  for (int i = 0; i < 4; i++)
#pragma unroll
    for (int j = 0; j < 4; j++) acc[i][j] = (f32x4){0.f, 0.f, 0.f, 0.f};

  for (int k0 = 0; k0 < DD; k0 += 32) {
    __syncthreads();
#pragma unroll
    for (int c = 0; c < 2; c++) {
      int r = c * 64 + w * 16 + lrow;
      __builtin_amdgcn_global_load_lds(
          (const __attribute__((address_space(1))) unsigned int*)(Xbf + (size_t)(row0 + r) * DD + k0 + lk),
          (__attribute__((address_space(3))) unsigned int*)(As + c * 2048 + w * 512),
          16, 0, 0);
      __builtin_amdgcn_global_load_lds(
          (const __attribute__((address_space(1))) unsigned int*)(Wt + (size_t)(col0 + r) * DD + k0 + lk),
          (__attribute__((address_space(3))) unsigned int*)(Bs + c * 2048 + w * 512),
          16, 0, 0);
    }
    __syncthreads();
    bf16x8 af[4], bfr[4];
#pragma unroll
    for (int i = 0; i < 4; i++) {
      af[i]  = *(const bf16x8*)&As[(wr + i * 16 + (lane & 15)) * 32 + (lane >> 4) * 8];
      bfr[i] = *(const bf16x8*)&Bs[(wc + i * 16 + (lane & 15)) * 32 + (lane >> 4) * 8];
    }
#pragma unroll
    for (int mi = 0; mi < 4; mi++)
#pragma unroll
      for (int ni = 0; ni < 4; ni++)
        acc[mi][ni] = __builtin_amdgcn_mfma_f32_16x16x32_bf16(af[mi], bfr[ni], acc[mi][ni], 0, 0, 0);
  }
  // epilogue: D[row=(lane>>4)*4+reg][col=lane&15] (+bias), store bf16
#pragma unroll
  for (int ni = 0; ni < 4; ni++) {
    int col = col0 + wc + ni * 16 + (lane & 15);
    float bias = bcat[col];
#pragma unroll
    for (int mi = 0; mi < 4; mi++) {
      int rbase = row0 + wr + mi * 16 + (lane >> 4) * 4;
#pragma unroll
      for (int r = 0; r < 4; r++) {
        float v = acc[mi][ni][r] + bias;
        Ocat[(size_t)(rbase + r) * NCAT + col] = f2bf(v);
      }
    }
  }
}

// ---------------------------------------------------------------
// Kernel 3: per-(segment, chunk) S = K_c^T V_c (k rows routing-masked)
// ---------------------------------------------------------------
__global__ __launch_bounds__(256) void chunk_kv(
    const unsigned short* __restrict__ Ocat,
    const int2* __restrict__ idxb, float* __restrict__ Sbuf) {
  __shared__ float Kc[CH * HD];
  __shared__ float Vc[CH * HD];
  const int chunk = blockIdx.x, seg = blockIdx.y;
  const int b = seg / MP1, m = seg % MP1;
  const int t0 = chunk * CH;
  const int tid = threadIdx.x;
#pragma unroll
  for (int u = 0; u < 4; u++) {
    int idx = tid + u * 256;
    int row = idx >> 4, c4 = (idx & 15) * 4;
    int tokrow = (t0 + row) * BB + b;
    float flag = 1.f;
    if (m != 0) { int2 ix = idxb[tokrow]; flag = (ix.x == m || ix.y == m) ? 1.f : 0.f; }
    const unsigned short* base = Ocat + (size_t)tokrow * NCAT + m * 64 + c4;
    ushort4 kv = *(const ushort4*)(base + 64);    // K block
    ushort4 vv = *(const ushort4*)(base + 640);   // V block
    Kc[row * 64 + c4 + 0] = bf2f(kv.x) * flag;
    Kc[row * 64 + c4 + 1] = bf2f(kv.y) * flag;
    Kc[row * 64 + c4 + 2] = bf2f(kv.z) * flag;
    Kc[row * 64 + c4 + 3] = bf2f(kv.w) * flag;
    Vc[row * 64 + c4 + 0] = bf2f(vv.x);
    Vc[row * 64 + c4 + 1] = bf2f(vv.y);
    Vc[row * 64 + c4 + 2] = bf2f(vv.z);
    Vc[row * 64 + c4 + 3] = bf2f(vv.w);
  }
  __syncthreads();
  const int r0 = (tid >> 4) * 4, c0 = (tid & 15) * 4;
  float acc[4][4];
#pragma unroll
  for (int v = 0; v < 4; v++)
#pragma unroll
    for (int w = 0; w < 4; w++) acc[v][w] = 0.f;
  for (int tok = 0; tok < CH; tok++) {
    float k0 = Kc[tok * 64 + r0 + 0];
    float k1 = Kc[tok * 64 + r0 + 1];
    float k2 = Kc[tok * 64 + r0 + 2];
    float k3 = Kc[tok * 64 + r0 + 3];
    float4 vv = *(const float4*)&Vc[tok * 64 + c0];
    acc[0][0] += k0 * vv.x; acc[0][1] += k0 * vv.y; acc[0][2] += k0 * vv.z; acc[0][3] += k0 * vv.w;
    acc[1][0] += k1 * vv.x; acc[1][1] += k1 * vv.y; acc[1][2] += k1 * vv.z; acc[1][3] += k1 * vv.w;
    acc[2][0] += k2 * vv.x; acc[2][1] += k2 * vv.y; acc[2][2] += k2 * vv.z; acc[2][3] += k2 * vv.w;
    acc[3][0] += k3 * vv.x; acc[3][1] += k3 * vv.y; acc[3][2] += k3 * vv.z; acc[3][3] += k3 * vv.w;
  }
  float* Sp = Sbuf + ((size_t)seg * NC + chunk) * 4096;
#pragma unroll
  for (int v = 0; v < 4; v++)
    *(float4*)&Sp[(r0 + v) * 64 + c0] = make_float4(acc[v][0], acc[v][1], acc[v][2], acc[v][3]);
}

// ---------------------------------------------------------------
// Kernel 4: per-segment exclusive scan over chunks (in place, fp32)
// ---------------------------------------------------------------
__global__ __launch_bounds__(256) void scan_kernel(
    const float* __restrict__ M0, float* __restrict__ Sbuf) {
  const int seg = blockIdx.x;
  const int tid = threadIdx.x;
  float run[16];
#pragma unroll
  for (int u = 0; u < 16; u++) run[u] = M0[tid + u * 256];
  float* base = Sbuf + (size_t)seg * NC * 4096;
  for (int c = 0; c < NC; c++) {
    float* p = base + c * 4096;
#pragma unroll
    for (int u = 0; u < 16; u++) {
      float s = p[tid + u * 256];
      p[tid + u * 256] = run[u];
      run[u] += s;
    }
  }
}

// ---------------------------------------------------------------
// Kernel 5: O = Q_c @ M_state + tril(Q K^T) @ V_c ; alpha-scaled scatter
// ---------------------------------------------------------------
__global__ __launch_bounds__(256) void chunk_out(
    const unsigned short* __restrict__ Ocat, const float* __restrict__ Sbuf,
    const int2* __restrict__ idxb, const float2* __restrict__ alfb,
    float* __restrict__ out) {
  __shared__ float QP[CH * HD];
  __shared__ float Kt[HD * CH];
  __shared__ float Vc[CH * HD];
  __shared__ float Ms[HD * HD];
  const int chunk = blockIdx.x, seg = blockIdx.y;
  const int b = seg / MP1, m = seg % MP1;
  const int t0 = chunk * CH;
  const int tid = threadIdx.x;
  {
    const float* Mp = Sbuf + ((size_t)seg * NC + chunk) * 4096;
#pragma unroll
    for (int u = 0; u < 4; u++) {
      int idx = tid + u * 256;
      *(float4*)&Ms[idx * 4] = *(const float4*)&Mp[idx * 4];
      int row = idx >> 4, c4 = (idx & 15) * 4;
      int tokrow = (t0 + row) * BB + b;
      float flag = 1.f;
      if (m != 0) { int2 ix = idxb[tokrow]; flag = (ix.x == m || ix.y == m) ? 1.f : 0.f; }
      const unsigned short* base = Ocat + (size_t)tokrow * NCAT;
      ushort4 q  = *(const ushort4*)(base + c4);
      ushort4 kv = *(const ushort4*)(base + 64 + m * 64 + c4);
      ushort4 vv = *(const ushort4*)(base + 640 + m * 64 + c4);
      QP[row * 64 + c4 + 0] = bf2f(q.x);
      QP[row * 64 + c4 + 1] = bf2f(q.y);
      QP[row * 64 + c4 + 2] = bf2f(q.z);
      QP[row * 64 + c4 + 3] = bf2f(q.w);
      Kt[(c4 + 0) * 64 + row] = bf2f(kv.x) * flag;
      Kt[(c4 + 1) * 64 + row] = bf2f(kv.y) * flag;
      Kt[(c4 + 2) * 64 + row] = bf2f(kv.z) * flag;
      Kt[(c4 + 3) * 64 + row] = bf2f(kv.w) * flag;
      Vc[row * 64 + c4 + 0] = bf2f(vv.x);
      Vc[row * 64 + c4 + 1] = bf2f(vv.y);
      Vc[row * 64 + c4 + 2] = bf2f(vv.z);
      Vc[row * 64 + c4 + 3] = bf2f(vv.w);
    }
  }
  __syncthreads();
  const int ir0 = (tid >> 4) * 4;
  const int c0  = (tid & 15) * 4;
  float oacc[4][4], pv[4][4];
#pragma unroll
  for (int v = 0; v < 4; v++)
#pragma unroll
    for (int w = 0; w < 4; w++) { oacc[v][w] = 0.f; pv[v][w] = 0.f; }
  for (int kk = 0; kk < 64; kk++) {
    float q0 = QP[(ir0 + 0) * 64 + kk];
    float q1 = QP[(ir0 + 1) * 64 + kk];
    float q2 = QP[(ir0 + 2) * 64 + kk];
    float q3 = QP[(ir0 + 3) * 64 + kk];
    float4 mv = *(const float4*)&Ms[kk * 64 + c0];
    float4 kv = *(const float4*)&Kt[kk * 64 + c0];
    oacc[0][0] += q0 * mv.x; oacc[0][1] += q0 * mv.y; oacc[0][2] += q0 * mv.z; oacc[0][3] += q0 * mv.w;
    oacc[1][0] += q1 * mv.x; oacc[1][1] += q1 * mv.y; oacc[1][2] += q1 * mv.z; oacc[1][3] += q1 * mv.w;
    oacc[2][0] += q2 * mv.x; oacc[2][1] += q2 * mv.y; oacc[2][2] += q2 * mv.z; oacc[2][3] += q2 * mv.w;
    oacc[3][0] += q3 * mv.x; oacc[3][1] += q3 * mv.y; oacc[3][2] += q3 * mv.z; oacc[3][3] += q3 * mv.w;
    pv[0][0] += q0 * kv.x; pv[0][1] += q0 * kv.y; pv[0][2] += q0 * kv.z; pv[0][3] += q0 * kv.w;
    pv[1][0] += q1 * kv.x; pv[1][1] += q1 * kv.y; pv[1][2] += q1 * kv.z; pv[1][3] += q1 * kv.w;
    pv[2][0] += q2 * kv.x; pv[2][1] += q2 * kv.y; pv[2][2] += q2 * kv.z; pv[2][3] += q2 * kv.w;
    pv[3][0] += q3 * kv.x; pv[3][1] += q3 * kv.y; pv[3][2] += q3 * kv.z; pv[3][3] += q3 * kv.w;
  }
#pragma unroll
  for (int v = 0; v < 4; v++)
#pragma unroll
    for (int w = 0; w < 4; w++)
      if (c0 + w > ir0 + v) pv[v][w] = 0.f;
  __syncthreads();
#pragma unroll
  for (int v = 0; v < 4; v++)
    *(float4*)&QP[(ir0 + v) * 64 + c0] = make_float4(pv[v][0], pv[v][1], pv[v][2], pv[v][3]);
  __syncthreads();
  for (int j = 0; j < 64; j++) {
    float p0 = QP[(ir0 + 0) * 64 + j];
    float p1 = QP[(ir0 + 1) * 64 + j];
    float p2 = QP[(ir0 + 2) * 64 + j];
    float p3 = QP[(ir0 + 3) * 64 + j];
    float4 vv = *(const float4*)&Vc[j * 64 + c0];
    oacc[0][0] += p0 * vv.x; oacc[0][1] += p0 * vv.y; oacc[0][2] += p0 * vv.z; oacc[0][3] += p0 * vv.w;
    oacc[1][0] += p1 * vv.x; oacc[1][1] += p1 * vv.y; oacc[1][2] += p1 * vv.z; oacc[1][3] += p1 * vv.w;
    oacc[2][0] += p2 * vv.x; oacc[2][1] += p2 * vv.y; oacc[2][2] += p2 * vv.z; oacc[2][3] += p2 * vv.w;
    oacc[3][0] += p3 * vv.x; oacc[3][1] += p3 * vv.y; oacc[3][2] += p3 * vv.z; oacc[3][3] += p3 * vv.w;
  }
#pragma unroll
  for (int v = 0; v < 4; v++) {
    int i = ir0 + v;
    int tokrow = (t0 + i) * BB + b;
    float alpha = 1.f;
    bool routed = true;
    if (m != 0) {
      int2 ix = idxb[tokrow];
      if (ix.x == m)      alpha = alfb[tokrow].x;
      else if (ix.y == m) alpha = alfb[tokrow].y;
      else routed = false;
    }
    if (routed) {
#pragma unroll
      for (int w = 0; w < 4; w++)
        atomicAdd(&out[(size_t)tokrow * HD + c0 + w], alpha * oacc[v][w]);
    }
  }
}

// ---------------------------------------------------------------
extern "C" void kernel_launch(void* const* d_in, const int* in_sizes, int n_in,
                              void* d_out, int out_size, void* d_ws, size_t ws_size,
                              hipStream_t stream) {
  const float* X  = (const float*)d_in[0];
  const float* M0 = (const float*)d_in[1];
  const float* Wq = (const float*)d_in[2];
  const float* bq = (const float*)d_in[3];
  const float* Wk = (const float*)d_in[4];
  const float* bk = (const float*)d_in[5];
  const float* Wv = (const float*)d_in[6];
  const float* bv = (const float*)d_in[7];
  const float* Wg = (const float*)d_in[8];
  const float* bg = (const float*)d_in[9];

  char* ws = (char*)d_ws;
  unsigned short* Xbf  = (unsigned short*)(ws);                  //  33,554,432 B
  unsigned short* Wt   = (unsigned short*)(ws + 33554432ULL);    //   2,621,440 B
  float*          bcat = (float*)         (ws + 36175872ULL);    //       5,120 B
  unsigned short* Ocat = (unsigned short*)(ws + 36184064ULL);    //  41,943,040 B
  float*          Sbuf = (float*)         (ws + 78127104ULL);    //  37,748,736 B
  int2*           idxb = (int2*)          (ws + 115875840ULL);   //     131,072 B
  float2*         alfb = (float2*)        (ws + 116006912ULL);   //     131,072 B

  float* out = (float*)d_out;
  hipMemsetAsync(d_out, 0, (size_t)out_size * sizeof(float), stream);

  cast_x<<<NTOK * DD / (256 * 4), 256, 0, stream>>>(X, Xbf);
  cast_w<<<NCAT * DD / 256, 256, 0, stream>>>(Wq, Wk, Wv, bq, bk, bv, Wt, bcat);
  gate_kernel<<<NTOK / 4, 256, 0, stream>>>(X, Wg, bg, idxb, alfb);
  proj_mfma<<<dim3(NCAT / 128, NTOK / 128), 256, 0, stream>>>(Xbf, Wt, bcat, Ocat);
  chunk_kv<<<dim3(NC, NSEG), 256, 0, stream>>>(Ocat, idxb, Sbuf);
  scan_kernel<<<NSEG, 256, 0, stream>>>(M0, Sbuf);
  chunk_out<<<dim3(NC, NSEG), 256, 0, stream>>>(Ocat, Sbuf, idxb, alfb, out);
}

// Round 3
// 295.828 us; speedup vs baseline: 2.6094x; 1.1432x over previous
//
#include <hip/hip_runtime.h>

#define TT   2048
#define BB   8
#define DD   1024
#define HD   64        // head dim d
#define MP1  9         // NM + 1
#define NTOK (TT*BB)   // 16384
#define CH   64        // chunk length
#define NC   (TT/CH)   // 32 chunks
#define NSEG (BB*MP1)  // 72 segments
#define NCAT 1280      // 64 Q + 576 K + 576 V + 64 pad
#define LDP  72        // padded LDS row stride (16B-aligned, rotates banks)

typedef __attribute__((ext_vector_type(8))) short bf16x8;
typedef __attribute__((ext_vector_type(4))) float f32x4;

union U8 { uint4 v; unsigned short s[8]; };

static __device__ __forceinline__ unsigned short f2bf(float f) {
  union { float f; unsigned u; } c; c.f = f;
  unsigned r = (c.u + 0x7FFF + ((c.u >> 16) & 1)) >> 16;   // RNE
  return (unsigned short)r;
}

// ---------------------------------------------------------------
// Build Wt[n][k] (bf16, transposed concat of Wq|Wk|Wv|0) and bcat
// ---------------------------------------------------------------
__global__ __launch_bounds__(256) void cast_w(
    const float* __restrict__ Wq, const float* __restrict__ Wk,
    const float* __restrict__ Wv, const float* __restrict__ bq,
    const float* __restrict__ bk, const float* __restrict__ bv,
    unsigned short* __restrict__ Wt, float* __restrict__ bcat) {
  int idx = blockIdx.x * 256 + threadIdx.x;     // over 1280*1024
  int n = idx >> 10, k = idx & 1023;
  float v = 0.f;
  if (n < 64)        v = Wq[k * 64 + n];
  else if (n < 640)  v = Wk[k * 576 + (n - 64)];
  else if (n < 1216) v = Wv[k * 576 + (n - 640)];
  Wt[idx] = f2bf(v);
  if (idx < NCAT) {
    float b = 0.f;
    if (idx < 64)        b = bq[idx];
    else if (idx < 640)  b = bk[idx - 64];
    else if (idx < 1216) b = bv[idx - 640];
    bcat[idx] = b;
  }
}

// ---------------------------------------------------------------
// Gating (fp32, exact top-2) + fused X -> bf16 cast
// ---------------------------------------------------------------
__global__ __launch_bounds__(256) void gate_kernel(
    const float* __restrict__ X, const float* __restrict__ Wg,
    const float* __restrict__ bg,
    int2* __restrict__ idxb, float2* __restrict__ alfb,
    unsigned short* __restrict__ Xbf) {
  __shared__ float wgT[8 * DD];
  const int tid = threadIdx.x;
  for (int idx = tid; idx < 8 * DD; idx += 256) {
    int i = idx >> 3, j = idx & 7;
    wgT[j * DD + i] = Wg[idx];
  }
  __syncthreads();
  const int lane = tid & 63, wave = tid >> 6;
  const int tok  = blockIdx.x * 4 + wave;
  const float* xr = X + (size_t)tok * DD;
  unsigned short* xbr = Xbf + (size_t)tok * DD;
  float p[8] = {0.f,0.f,0.f,0.f,0.f,0.f,0.f,0.f};
  for (int it = 0; it < 16; it++) {
    int i = it * 64 + lane;
    float x = xr[i];
    xbr[i] = f2bf(x);
#pragma unroll
    for (int j = 0; j < 8; j++) p[j] += x * wgT[j * DD + i];
  }
#pragma unroll
  for (int j = 0; j < 8; j++) {
    float v = p[j];
#pragma unroll
    for (int off = 32; off > 0; off >>= 1) v += __shfl_xor(v, off);
    p[j] = v + bg[j];
  }
  if (lane == 0) {
    int i1 = 0; float z1 = p[0];
#pragma unroll
    for (int j = 1; j < 8; j++) if (p[j] > z1) { z1 = p[j]; i1 = j; }
    int i2 = -1; float z2 = -3.0e38f;
#pragma unroll
    for (int j = 0; j < 8; j++) if (j != i1 && p[j] > z2) { z2 = p[j]; i2 = j; }
    float e   = expf(z2 - z1);
    float inv = 1.0f / (1.0f + e);
    idxb[tok] = make_int2(i1 + 1, i2 + 1);
    alfb[tok] = make_float2(inv, e * inv);
  }
}

// ---------------------------------------------------------------
// Projection GEMM, bf16 MFMA (m97 structure):
// (16384 x 1024) @ (1024 x 1280) -> Ocat bf16 (+bias)
// ---------------------------------------------------------------
__global__ __launch_bounds__(256) void proj_mfma(
    const unsigned short* __restrict__ Xbf, const unsigned short* __restrict__ Wt,
    const float* __restrict__ bcat, unsigned short* __restrict__ Ocat) {
  __shared__ unsigned short As[128 * 32];
  __shared__ unsigned short Bs[128 * 32];
  const int tid  = threadIdx.x;
  const int lane = tid & 63, w = tid >> 6;
  const int row0 = blockIdx.y * 128;
  const int col0 = blockIdx.x * 128;
  const int wr = (w >> 1) * 64, wc = (w & 1) * 64;
  const int lrow = lane >> 2;
  const int lk   = (lane & 3) * 8;

  f32x4 acc[4][4];
#pragma unroll
  for (int i = 0; i < 4; i++)
#pragma unroll
    for (int j = 0; j < 4; j++) acc[i][j] = (f32x4){0.f, 0.f, 0.f, 0.f};

  for (int k0 = 0; k0 < DD; k0 += 32) {
    __syncthreads();
#pragma unroll
    for (int c = 0; c < 2; c++) {
      int r = c * 64 + w * 16 + lrow;
      __builtin_amdgcn_global_load_lds(
          (const __attribute__((address_space(1))) unsigned int*)(Xbf + (size_t)(row0 + r) * DD + k0 + lk),
          (__attribute__((address_space(3))) unsigned int*)(As + c * 2048 + w * 512),
          16, 0, 0);
      __builtin_amdgcn_global_load_lds(
          (const __attribute__((address_space(1))) unsigned int*)(Wt + (size_t)(col0 + r) * DD + k0 + lk),
          (__attribute__((address_space(3))) unsigned int*)(Bs + c * 2048 + w * 512),
          16, 0, 0);
    }
    __syncthreads();
    bf16x8 af[4], bfr[4];
#pragma unroll
    for (int i = 0; i < 4; i++) {
      af[i]  = *(const bf16x8*)&As[(wr + i * 16 + (lane & 15)) * 32 + (lane >> 4) * 8];
      bfr[i] = *(const bf16x8*)&Bs[(wc + i * 16 + (lane & 15)) * 32 + (lane >> 4) * 8];
    }
#pragma unroll
    for (int mi = 0; mi < 4; mi++)
#pragma unroll
      for (int ni = 0; ni < 4; ni++)
        acc[mi][ni] = __builtin_amdgcn_mfma_f32_16x16x32_bf16(af[mi], bfr[ni], acc[mi][ni], 0, 0, 0);
  }
#pragma unroll
  for (int ni = 0; ni < 4; ni++) {
    int col = col0 + wc + ni * 16 + (lane & 15);
    float bias = bcat[col];
#pragma unroll
    for (int mi = 0; mi < 4; mi++) {
      int rbase = row0 + wr + mi * 16 + (lane >> 4) * 4;
#pragma unroll
      for (int r = 0; r < 4; r++) {
        float v = acc[mi][ni][r] + bias;
        Ocat[(size_t)(rbase + r) * NCAT + col] = f2bf(v);
      }
    }
  }
}

// ---------------------------------------------------------------
// Kernel: per-(segment, chunk) S = K_c^T V_c via MFMA
// KTs[r][tok], VTs[c][tok] (transposed, stride LDP)
// ---------------------------------------------------------------
__global__ __launch_bounds__(256) void chunk_kv(
    const unsigned short* __restrict__ Ocat,
    const int2* __restrict__ idxb, float* __restrict__ Sbuf) {
  __shared__ unsigned short KTs[64 * LDP];
  __shared__ unsigned short VTs[64 * LDP];
  const int chunk = blockIdx.x, seg = blockIdx.y;
  const int b = seg / MP1, m = seg % MP1;
  const int t0 = chunk * CH;
  const int tid = threadIdx.x;
  {
    int row = tid >> 2, c16 = (tid & 3) << 4;
    int tokrow = (t0 + row) * BB + b;
    bool on = true;
    if (m) { int2 ix = idxb[tokrow]; on = (ix.x == m || ix.y == m); }
    const unsigned short* obase = Ocat + (size_t)tokrow * NCAT + m * 64;
    U8 k0, k1, v0, v1;
    k0.v = *(const uint4*)(obase + 64 + c16);
    k1.v = *(const uint4*)(obase + 64 + c16 + 8);
    v0.v = *(const uint4*)(obase + 640 + c16);
    v1.v = *(const uint4*)(obase + 640 + c16 + 8);
    if (!on) { uint4 z = {0,0,0,0}; k0.v = z; k1.v = z; }
#pragma unroll
    for (int j = 0; j < 8; j++) {
      KTs[(c16 + j) * LDP + row]     = k0.s[j];
      KTs[(c16 + 8 + j) * LDP + row] = k1.s[j];
      VTs[(c16 + j) * LDP + row]     = v0.s[j];
      VTs[(c16 + 8 + j) * LDP + row] = v1.s[j];
    }
  }
  __syncthreads();
  const int lane = tid & 63, w = tid >> 6;
  const int quad = lane >> 4, l15 = lane & 15;
  const unsigned short* arow = &KTs[(w * 16 + l15) * LDP];
  bf16x8 a0 = *(const bf16x8*)(arow + quad * 8);
  bf16x8 a1 = *(const bf16x8*)(arow + 32 + quad * 8);
  f32x4 acc[4];
#pragma unroll
  for (int n = 0; n < 4; n++) {
    const unsigned short* brow = &VTs[(n * 16 + l15) * LDP];
    acc[n] = __builtin_amdgcn_mfma_f32_16x16x32_bf16(a0, *(const bf16x8*)(brow + quad * 8),
                                                     (f32x4){0.f,0.f,0.f,0.f}, 0, 0, 0);
    acc[n] = __builtin_amdgcn_mfma_f32_16x16x32_bf16(a1, *(const bf16x8*)(brow + 32 + quad * 8),
                                                     acc[n], 0, 0, 0);
  }
  float* Sp = Sbuf + ((size_t)seg * NC + chunk) * 4096;
#pragma unroll
  for (int n = 0; n < 4; n++)
#pragma unroll
    for (int r = 0; r < 4; r++)
      Sp[(w * 16 + quad * 4 + r) * 64 + n * 16 + l15] = acc[n][r];
}

// ---------------------------------------------------------------
// Kernel: per-segment exclusive scan over chunks, 4 col-slabs/seg
// ---------------------------------------------------------------
__global__ __launch_bounds__(256) void scan_kernel(
    const float* __restrict__ M0, float* __restrict__ Sbuf) {
  const int seg = blockIdx.x >> 2, slab = blockIdx.x & 3;
  const int tid = threadIdx.x;
  const int off = (tid >> 2) * 64 + slab * 16 + (tid & 3) * 4;
  float4 run = *(const float4*)&M0[off];
  float* base = Sbuf + (size_t)seg * NC * 4096;
  for (int c = 0; c < NC; c++) {
    float* p = base + c * 4096 + off;
    float4 s = *(const float4*)p;
    *(float4*)p = run;
    run.x += s.x; run.y += s.y; run.z += s.z; run.w += s.w;
  }
}

// ---------------------------------------------------------------
// Kernel: O = Q@M_state + tril(Q K^T)@V via MFMA; alpha scatter
// Qs/Ks natural [tok][dim]; MsT [c][k]; VTs [c][tok]; all stride LDP
// Qs strip reused per-wave to round-trip P (wave-private, no barrier)
// ---------------------------------------------------------------
__global__ __launch_bounds__(256) void chunk_out(
    const unsigned short* __restrict__ Ocat, const float* __restrict__ Sbuf,
    const int2* __restrict__ idxb, const float2* __restrict__ alfb,
    float* __restrict__ out) {
  __shared__ unsigned short Qs[64 * LDP];
  __shared__ unsigned short Ks[64 * LDP];
  __shared__ unsigned short MsT[64 * LDP];
  __shared__ unsigned short VTs[64 * LDP];
  const int chunk = blockIdx.x, seg = blockIdx.y;
  const int b = seg / MP1, m = seg % MP1;
  const int t0 = chunk * CH;
  const int tid = threadIdx.x;
  {
    int row = tid >> 2, c16 = (tid & 3) << 4;
    int tokrow = (t0 + row) * BB + b;
    bool on = true;
    if (m) { int2 ix = idxb[tokrow]; on = (ix.x == m || ix.y == m); }
    const unsigned short* obase = Ocat + (size_t)tokrow * NCAT;
    // Q natural
    *(uint4*)&Qs[row * LDP + c16]     = *(const uint4*)(obase + c16);
    *(uint4*)&Qs[row * LDP + c16 + 8] = *(const uint4*)(obase + c16 + 8);
    // K natural, masked
    uint4 k0 = *(const uint4*)(obase + 64 + m * 64 + c16);
    uint4 k1 = *(const uint4*)(obase + 64 + m * 64 + c16 + 8);
    if (!on) { uint4 z = {0,0,0,0}; k0 = z; k1 = z; }
    *(uint4*)&Ks[row * LDP + c16]     = k0;
    *(uint4*)&Ks[row * LDP + c16 + 8] = k1;
    // V transposed
    U8 v0, v1;
    v0.v = *(const uint4*)(obase + 640 + m * 64 + c16);
    v1.v = *(const uint4*)(obase + 640 + m * 64 + c16 + 8);
#pragma unroll
    for (int j = 0; j < 8; j++) {
      VTs[(c16 + j) * LDP + row]     = v0.s[j];
      VTs[(c16 + 8 + j) * LDP + row] = v1.s[j];
    }
    // M_state fp32 -> bf16, transposed
    const float* Mp = Sbuf + ((size_t)seg * NC + chunk) * 4096 + row * 64 + c16;
#pragma unroll
    for (int jj = 0; jj < 4; jj++) {
      float4 f = *(const float4*)(Mp + jj * 4);
      MsT[(c16 + jj * 4 + 0) * LDP + row] = f2bf(f.x);
      MsT[(c16 + jj * 4 + 1) * LDP + row] = f2bf(f.y);
      MsT[(c16 + jj * 4 + 2) * LDP + row] = f2bf(f.z);
      MsT[(c16 + jj * 4 + 3) * LDP + row] = f2bf(f.w);
    }
  }
  __syncthreads();
  const int lane = tid & 63, w = tid >> 6;
  const int quad = lane >> 4, l15 = lane & 15;
  unsigned short* qrow = &Qs[(w * 16 + l15) * LDP];
  bf16x8 aq0 = *(const bf16x8*)(qrow + quad * 8);
  bf16x8 aq1 = *(const bf16x8*)(qrow + 32 + quad * 8);
  f32x4 po[4], pp[4];
#pragma unroll
  for (int n = 0; n < 4; n++) {
    const unsigned short* mrow = &MsT[(n * 16 + l15) * LDP];
    const unsigned short* krow = &Ks[(n * 16 + l15) * LDP];
    po[n] = __builtin_amdgcn_mfma_f32_16x16x32_bf16(aq0, *(const bf16x8*)(mrow + quad * 8),
                                                    (f32x4){0.f,0.f,0.f,0.f}, 0, 0, 0);
    po[n] = __builtin_amdgcn_mfma_f32_16x16x32_bf16(aq1, *(const bf16x8*)(mrow + 32 + quad * 8),
                                                    po[n], 0, 0, 0);
    pp[n] = __builtin_amdgcn_mfma_f32_16x16x32_bf16(aq0, *(const bf16x8*)(krow + quad * 8),
                                                    (f32x4){0.f,0.f,0.f,0.f}, 0, 0, 0);
    pp[n] = __builtin_amdgcn_mfma_f32_16x16x32_bf16(aq1, *(const bf16x8*)(krow + 32 + quad * 8),
                                                    pp[n], 0, 0, 0);
  }
  // causal mask (inclusive diag), bf16, round-trip P via own Q strip
#pragma unroll
  for (int n = 0; n < 4; n++)
#pragma unroll
    for (int r = 0; r < 4; r++) {
      int i = w * 16 + quad * 4 + r, j = n * 16 + l15;
      Qs[i * LDP + j] = (j <= i) ? f2bf(pp[n][r]) : (unsigned short)0;
    }
  bf16x8 ap0 = *(const bf16x8*)(qrow + quad * 8);
  bf16x8 ap1 = *(const bf16x8*)(qrow + 32 + quad * 8);
#pragma unroll
  for (int n = 0; n < 4; n++) {
    const unsigned short* vrow = &VTs[(n * 16 + l15) * LDP];
    po[n] = __builtin_amdgcn_mfma_f32_16x16x32_bf16(ap0, *(const bf16x8*)(vrow + quad * 8),
                                                    po[n], 0, 0, 0);
    po[n] = __builtin_amdgcn_mfma_f32_16x16x32_bf16(ap1, *(const bf16x8*)(vrow + 32 + quad * 8),
                                                    po[n], 0, 0, 0);
  }
  // epilogue: routing weight + atomic scatter
  float alpha_r[4]; int tok_r[4]; bool rt_r[4];
#pragma unroll
  for (int r = 0; r < 4; r++) {
    int i = w * 16 + quad * 4 + r;
    int tr = (t0 + i) * BB + b;
    tok_r[r] = tr; alpha_r[r] = 1.f; rt_r[r] = true;
    if (m) {
      int2 ix = idxb[tr];
      if (ix.x == m)      alpha_r[r] = alfb[tr].x;
      else if (ix.y == m) alpha_r[r] = alfb[tr].y;
      else rt_r[r] = false;
    }
  }
#pragma unroll
  for (int n = 0; n < 4; n++)
#pragma unroll
    for (int r = 0; r < 4; r++)
      if (rt_r[r])
        atomicAdd(&out[(size_t)tok_r[r] * HD + n * 16 + l15], alpha_r[r] * po[n][r]);
}

// ---------------------------------------------------------------
extern "C" void kernel_launch(void* const* d_in, const int* in_sizes, int n_in,
                              void* d_out, int out_size, void* d_ws, size_t ws_size,
                              hipStream_t stream) {
  const float* X  = (const float*)d_in[0];
  const float* M0 = (const float*)d_in[1];
  const float* Wq = (const float*)d_in[2];
  const float* bq = (const float*)d_in[3];
  const float* Wk = (const float*)d_in[4];
  const float* bk = (const float*)d_in[5];
  const float* Wv = (const float*)d_in[6];
  const float* bv = (const float*)d_in[7];
  const float* Wg = (const float*)d_in[8];
  const float* bg = (const float*)d_in[9];

  char* ws = (char*)d_ws;
  unsigned short* Xbf  = (unsigned short*)(ws);                  //  33,554,432 B
  unsigned short* Wt   = (unsigned short*)(ws + 33554432ULL);    //   2,621,440 B
  float*          bcat = (float*)         (ws + 36175872ULL);    //       5,120 B
  unsigned short* Ocat = (unsigned short*)(ws + 36184064ULL);    //  41,943,040 B
  float*          Sbuf = (float*)         (ws + 78127104ULL);    //  37,748,736 B
  int2*           idxb = (int2*)          (ws + 115875840ULL);   //     131,072 B
  float2*         alfb = (float2*)        (ws + 116006912ULL);   //     131,072 B

  float* out = (float*)d_out;
  hipMemsetAsync(d_out, 0, (size_t)out_size * sizeof(float), stream);

  cast_w<<<NCAT * DD / 256, 256, 0, stream>>>(Wq, Wk, Wv, bq, bk, bv, Wt, bcat);
  gate_kernel<<<NTOK / 4, 256, 0, stream>>>(X, Wg, bg, idxb, alfb, Xbf);
  proj_mfma<<<dim3(NCAT / 128, NTOK / 128), 256, 0, stream>>>(Xbf, Wt, bcat, Ocat);
  chunk_kv<<<dim3(NC, NSEG), 256, 0, stream>>>(Ocat, idxb, Sbuf);
  scan_kernel<<<NSEG * 4, 256, 0, stream>>>(M0, Sbuf);
  chunk_out<<<dim3(NC, NSEG), 256, 0, stream>>>(Ocat, Sbuf, idxb, alfb, out);
}